// Round 1
// baseline (860.825 us; speedup 1.0000x reference)
//
#include <hip/hip_runtime.h>
#include <hip/hip_fp16.h>

#define DI __device__ __forceinline__

constexpr int TH = 64, TW = 64;           // output tile
constexpr int IH = TH + 32, IW = TW + 32; // 96x96 input tile (16 halo)
constexpr float kC1 = 1.0e-4f;            // (0.01*1)^2
constexpr float kC2 = 9.0e-4f;            // (0.03*1)^2
constexpr float kALPHA = 0.025f;

DI float rcp_fast(float v) { return __builtin_amdgcn_rcpf(v); }

// ---- load NW fp16 values from LDS into fp32 regs (b64 granularity) ----
template<int NW>
DI void load_win(const __half* __restrict__ s, float* __restrict__ f) {
#pragma unroll
  for (int i = 0; i < NW / 4; ++i) {
    uint2 u = *reinterpret_cast<const uint2*>(s + 4 * i);
    __half2 a = *reinterpret_cast<__half2*>(&u.x);
    __half2 b = *reinterpret_cast<__half2*>(&u.y);
    f[4 * i + 0] = __low2float(a);
    f[4 * i + 1] = __high2float(a);
    f[4 * i + 2] = __low2float(b);
    f[4 * i + 3] = __high2float(b);
  }
}

DI void store4h(__half* __restrict__ d, float a0, float a1, float a2, float a3) {
  __half2 p = __floats2half2_rn(a0, a1);
  __half2 q = __floats2half2_rn(a2, a3);
  uint2 u;
  u.x = *reinterpret_cast<unsigned*>(&p);
  u.y = *reinterpret_cast<unsigned*>(&q);
  *reinterpret_cast<uint2*>(d) = u;
}

// ---- horizontal pass, maps (t, t^2) from one staged tile ----
template<int R>
DI void hpassAB(const __half* __restrict__ t, __half* __restrict__ h0,
                __half* __restrict__ h1, const float* __restrict__ wk, int tid) {
  constexpr int K = 2 * R + 1;
  constexpr int LO = (16 - R) & ~3;
  constexpr int NW = (((19 + R) | 3) + 1) - LO;
  constexpr int OFS = (16 - R) - LO;
  for (int q = 0; q < 6; ++q) {              // 96 rows * 16 colgroups / 256 thr
    int id = q * 256 + tid;
    int row = id >> 4, c0 = (id & 15) << 2;
    float f[NW];
    load_win<NW>(t + row * IW + c0 + LO, f);
    float a0 = 0, a1 = 0, a2 = 0, a3 = 0, b0 = 0, b1 = 0, b2 = 0, b3 = 0;
#pragma unroll
    for (int j = 0; j < K; ++j) {
      float w = wk[j];
      float v0 = f[OFS + j + 0], v1 = f[OFS + j + 1];
      float v2 = f[OFS + j + 2], v3 = f[OFS + j + 3];
      float t0 = w * v0, t1 = w * v1, t2 = w * v2, t3 = w * v3;
      a0 += t0; a1 += t1; a2 += t2; a3 += t3;
      b0 = fmaf(t0, v0, b0); b1 = fmaf(t1, v1, b1);
      b2 = fmaf(t2, v2, b2); b3 = fmaf(t3, v3, b3);
    }
    store4h(h0 + row * TW + c0, a0, a1, a2, a3);
    store4h(h1 + row * TW + c0, b0, b1, b2, b3);
  }
}

// ---- horizontal pass, map x*y (and |x-y| when LAST) ----
template<int R, bool LAST>
DI void hpassC(const __half* __restrict__ xt, const __half* __restrict__ yt,
               __half* __restrict__ h0, __half* __restrict__ h1,
               const float* __restrict__ wk, int tid) {
  constexpr int K = 2 * R + 1;
  constexpr int LO = (16 - R) & ~3;
  constexpr int NW = (((19 + R) | 3) + 1) - LO;
  constexpr int OFS = (16 - R) - LO;
  for (int q = 0; q < 6; ++q) {
    int id = q * 256 + tid;
    int row = id >> 4, c0 = (id & 15) << 2;
    float fx[NW], fy[NW];
    load_win<NW>(xt + row * IW + c0 + LO, fx);
    load_win<NW>(yt + row * IW + c0 + LO, fy);
    float pr[NW], df[LAST ? NW : 4];
#pragma unroll
    for (int i = 0; i < NW; ++i) {
      pr[i] = fx[i] * fy[i];
      if (LAST) df[i] = fabsf(fx[i] - fy[i]);
    }
    float a0 = 0, a1 = 0, a2 = 0, a3 = 0, b0 = 0, b1 = 0, b2 = 0, b3 = 0;
#pragma unroll
    for (int j = 0; j < K; ++j) {
      float w = wk[j];
      a0 = fmaf(w, pr[OFS + j + 0], a0); a1 = fmaf(w, pr[OFS + j + 1], a1);
      a2 = fmaf(w, pr[OFS + j + 2], a2); a3 = fmaf(w, pr[OFS + j + 3], a3);
      if (LAST) {
        b0 = fmaf(w, df[OFS + j + 0], b0); b1 = fmaf(w, df[OFS + j + 1], b1);
        b2 = fmaf(w, df[OFS + j + 2], b2); b3 = fmaf(w, df[OFS + j + 3], b3);
      }
    }
    store4h(h0 + row * TW + c0, a0, a1, a2, a3);
    if (LAST) store4h(h1 + row * TW + c0, b0, b1, b2, b3);
  }
}

// ---- vertical pass: 4 rows x 4 cols per thread, 1 (or 2) maps ----
template<int R, bool TWO>
DI void vpass(const __half* __restrict__ h0, const __half* __restrict__ h1,
              const float* __restrict__ wk, int tid,
              float* __restrict__ acc0, float* __restrict__ acc1) {
  constexpr int K = 2 * R + 1;
  const int rg = tid >> 4, cg = tid & 15;
  const int r0 = rg << 2, c0 = cg << 2;
#pragma unroll
  for (int t = 0; t < K + 3; ++t) {
    int lr = r0 + (16 - R) + t;
    uint2 u = *reinterpret_cast<const uint2*>(h0 + lr * TW + c0);
    __half2 ha = *reinterpret_cast<__half2*>(&u.x);
    __half2 hb = *reinterpret_cast<__half2*>(&u.y);
    float x0 = __low2float(ha), x1 = __high2float(ha);
    float x2 = __low2float(hb), x3 = __high2float(hb);
    float y0 = 0, y1 = 0, y2 = 0, y3 = 0;
    if (TWO) {
      uint2 v = *reinterpret_cast<const uint2*>(h1 + lr * TW + c0);
      __half2 hc = *reinterpret_cast<__half2*>(&v.x);
      __half2 hd = *reinterpret_cast<__half2*>(&v.y);
      y0 = __low2float(hc); y1 = __high2float(hc);
      y2 = __low2float(hd); y3 = __high2float(hd);
    }
#pragma unroll
    for (int rr = 0; rr < 4; ++rr) {
      int j = t - rr;
      if (j >= 0 && j < K) {   // folds at compile time after unroll
        float w = wk[j];
        acc0[rr * 4 + 0] = fmaf(w, x0, acc0[rr * 4 + 0]);
        acc0[rr * 4 + 1] = fmaf(w, x1, acc0[rr * 4 + 1]);
        acc0[rr * 4 + 2] = fmaf(w, x2, acc0[rr * 4 + 2]);
        acc0[rr * 4 + 3] = fmaf(w, x3, acc0[rr * 4 + 3]);
        if (TWO) {
          acc1[rr * 4 + 0] = fmaf(w, y0, acc1[rr * 4 + 0]);
          acc1[rr * 4 + 1] = fmaf(w, y1, acc1[rr * 4 + 1]);
          acc1[rr * 4 + 2] = fmaf(w, y2, acc1[rr * 4 + 2]);
          acc1[rr * 4 + 3] = fmaf(w, y3, acc1[rr * 4 + 3]);
        }
      }
    }
  }
}

template<int R, bool LAST>
DI void do_sigma(int sidx, const float* __restrict__ w1d,
                 const __half* __restrict__ xt, const __half* __restrict__ yt,
                 __half* __restrict__ hb0, __half* __restrict__ hb1,
                 float* __restrict__ PIcs, float* __restrict__ lM,
                 float* __restrict__ gl1, int tid) {
  const float* wk = w1d + sidx * 33 + (16 - R);
  float mux[16], ex2[16], muy[16], ey2[16], exy[16], vl1[16];
#pragma unroll
  for (int i = 0; i < 16; ++i) {
    mux[i] = 0; ex2[i] = 0; muy[i] = 0; ey2[i] = 0; exy[i] = 0; vl1[i] = 0;
  }
  hpassAB<R>(xt, hb0, hb1, wk, tid);
  __syncthreads();
  vpass<R, true>(hb0, hb1, wk, tid, mux, ex2);
  __syncthreads();
  hpassAB<R>(yt, hb0, hb1, wk, tid);
  __syncthreads();
  vpass<R, true>(hb0, hb1, wk, tid, muy, ey2);
  __syncthreads();
  hpassC<R, LAST>(xt, yt, hb0, hb1, wk, tid);
  __syncthreads();
  vpass<R, LAST>(hb0, hb1, wk, tid, exy, vl1);
  __syncthreads();
#pragma unroll
  for (int i = 0; i < 16; ++i) {
    float m2x = mux[i] * mux[i];
    float m2y = muy[i] * muy[i];
    float mxy = mux[i] * muy[i];
    float sx2 = ex2[i] - m2x, sy2 = ey2[i] - m2y, sxy = exy[i] - mxy;
    float cs = fmaf(2.f, sxy, kC2) * rcp_fast(sx2 + sy2 + kC2);
    PIcs[i] *= cs;
    if (LAST) {
      float l = fmaf(2.f, mxy, kC1) * rcp_fast(m2x + m2y + kC1);
      lM[i] *= l;
      gl1[i] += vl1[i];
    }
  }
}

// ---- extract 1D separable kernels: g[j] = mask[16][j] / sqrt(mask[16][16]) ----
__global__ void prep_k(const float* __restrict__ gm, float* __restrict__ w1d) {
  int t = threadIdx.x;
  if (t < 165) {
    int s = t / 33, j = t % 33;
    const float* m = gm + (3 * s) * (33 * 33);
    float g16 = sqrtf(m[16 * 33 + 16]);
    w1d[t] = m[16 * 33 + j] / g16;
  }
}

__global__ __launch_bounds__(256, 2)
void msloss_k(const float* __restrict__ x, const float* __restrict__ y,
              const float* __restrict__ w1d, float* __restrict__ out) {
  __shared__ __half xt[IH * IW];
  __shared__ __half yt[IH * IW];
  __shared__ __half hb0[IH * TW];
  __shared__ __half hb1[IH * TW];
  __shared__ float red[4];
  const int tid = threadIdx.x;
  const int ox = blockIdx.x * TW, oy = blockIdx.y * TH;
  const int b = blockIdx.z;

  float PIcs[16], lM[16], gl1[16];
#pragma unroll
  for (int i = 0; i < 16; ++i) { PIcs[i] = 1.f; lM[i] = 1.f; gl1[i] = 0.f; }

  for (int c = 0; c < 3; ++c) {
    const float* xp = x + (size_t)(b * 3 + c) * (512 * 512);
    const float* yp = y + (size_t)(b * 3 + c) * (512 * 512);
    // stage 96x96 fp32->fp16 tiles with zero halo (2304 float4 slots each)
    for (int t = 0; t < 9; ++t) {
      int idx = t * 256 + tid;
      int row = idx / 24, c4 = idx % 24;
      int gy = oy + row - 16, gx = ox + c4 * 4 - 16;
      bool ok = ((unsigned)gy < 512u) && ((unsigned)gx < 512u);
      float4 xv = make_float4(0.f, 0.f, 0.f, 0.f);
      float4 yv = make_float4(0.f, 0.f, 0.f, 0.f);
      if (ok) {
        xv = *reinterpret_cast<const float4*>(xp + gy * 512 + gx);
        yv = *reinterpret_cast<const float4*>(yp + gy * 512 + gx);
      }
      store4h(xt + row * IW + c4 * 4, xv.x, xv.y, xv.z, xv.w);
      store4h(yt + row * IW + c4 * 4, yv.x, yv.y, yv.z, yv.w);
    }
    __syncthreads();
    do_sigma<4, false>(0, w1d, xt, yt, hb0, hb1, PIcs, lM, gl1, tid);
    do_sigma<6, false>(1, w1d, xt, yt, hb0, hb1, PIcs, lM, gl1, tid);
    do_sigma<12, false>(2, w1d, xt, yt, hb0, hb1, PIcs, lM, gl1, tid);
    do_sigma<16, false>(3, w1d, xt, yt, hb0, hb1, PIcs, lM, gl1, tid);
    do_sigma<16, true>(4, w1d, xt, yt, hb0, hb1, PIcs, lM, gl1, tid);
    // do_sigma ends with __syncthreads(): safe to restage next channel
  }

  float s = 0.f;
#pragma unroll
  for (int i = 0; i < 16; ++i)
    s += kALPHA * (1.f - lM[i] * PIcs[i]) + ((1.f - kALPHA) / 3.f) * gl1[i];
#pragma unroll
  for (int off = 32; off > 0; off >>= 1) s += __shfl_down(s, off);
  if ((tid & 63) == 0) red[tid >> 6] = s;
  __syncthreads();
  if (tid == 0)
    atomicAdd(out, (red[0] + red[1] + red[2] + red[3]) *
                       (200.0f / (8.0f * 512.0f * 512.0f)));
}

extern "C" void kernel_launch(void* const* d_in, const int* in_sizes, int n_in,
                              void* d_out, int out_size, void* d_ws, size_t ws_size,
                              hipStream_t stream) {
  const float* x = (const float*)d_in[0];
  const float* y = (const float*)d_in[1];
  const float* gm = (const float*)d_in[2];
  float* out = (float*)d_out;
  float* w1d = (float*)d_ws;  // 165 floats of 1D kernels

  hipMemsetAsync(d_out, 0, out_size * sizeof(float), stream);
  prep_k<<<1, 256, 0, stream>>>(gm, w1d);
  msloss_k<<<dim3(8, 8, 8), 256, 0, stream>>>(x, y, w1d, out);
}

// Round 2
// 858.472 us; speedup vs baseline: 1.0027x; 1.0027x over previous
//
#include <hip/hip_runtime.h>
#include <hip/hip_fp16.h>

#define DI __device__ __forceinline__

constexpr int TH = 64, TW = 64;           // output tile
constexpr int IH = TH + 32, IW = TW + 32; // 96x96 input tile (16 halo)
constexpr float kC1 = 1.0e-4f;            // (0.01*1)^2
constexpr float kC2 = 9.0e-4f;            // (0.03*1)^2
constexpr float kALPHA = 0.025f;

DI float rcp_fast(float v) { return __builtin_amdgcn_rcpf(v); }

// ---- load NW fp16 values from LDS into fp32 regs (b64 granularity) ----
template<int NW>
DI void load_win(const __half* __restrict__ s, float* __restrict__ f) {
#pragma unroll
  for (int i = 0; i < NW / 4; ++i) {
    uint2 u = *reinterpret_cast<const uint2*>(s + 4 * i);
    __half2 a = *reinterpret_cast<__half2*>(&u.x);
    __half2 b = *reinterpret_cast<__half2*>(&u.y);
    f[4 * i + 0] = __low2float(a);
    f[4 * i + 1] = __high2float(a);
    f[4 * i + 2] = __low2float(b);
    f[4 * i + 3] = __high2float(b);
  }
}

DI void store4h(__half* __restrict__ d, float a0, float a1, float a2, float a3) {
  __half2 p = __floats2half2_rn(a0, a1);
  __half2 q = __floats2half2_rn(a2, a3);
  uint2 u;
  u.x = *reinterpret_cast<unsigned*>(&p);
  u.y = *reinterpret_cast<unsigned*>(&q);
  *reinterpret_cast<uint2*>(d) = u;
}

// ---- horizontal pass, maps (t, t^2) from one staged tile ----
template<int R>
DI void hpassAB(const __half* __restrict__ t, __half* __restrict__ h0,
                __half* __restrict__ h1, const float* __restrict__ wk, int tid) {
  constexpr int K = 2 * R + 1;
  constexpr int LO = (16 - R) & ~3;
  constexpr int NW = (((19 + R) | 3) + 1) - LO;
  constexpr int OFS = (16 - R) - LO;
  for (int q = 0; q < 6; ++q) {              // 96 rows * 16 colgroups / 256 thr
    int id = q * 256 + tid;
    int row = id >> 4, c0 = (id & 15) << 2;
    float f[NW];
    load_win<NW>(t + row * IW + c0 + LO, f);
    float a0 = 0, a1 = 0, a2 = 0, a3 = 0, b0 = 0, b1 = 0, b2 = 0, b3 = 0;
#pragma unroll
    for (int j = 0; j < K; ++j) {
      float w = wk[j];
      float v0 = f[OFS + j + 0], v1 = f[OFS + j + 1];
      float v2 = f[OFS + j + 2], v3 = f[OFS + j + 3];
      float t0 = w * v0, t1 = w * v1, t2 = w * v2, t3 = w * v3;
      a0 += t0; a1 += t1; a2 += t2; a3 += t3;
      b0 = fmaf(t0, v0, b0); b1 = fmaf(t1, v1, b1);
      b2 = fmaf(t2, v2, b2); b3 = fmaf(t3, v3, b3);
    }
    store4h(h0 + row * TW + c0, a0, a1, a2, a3);
    store4h(h1 + row * TW + c0, b0, b1, b2, b3);
  }
}

// ---- horizontal pass, map x*y (and |x-y| when LAST) ----
// products/diffs computed on the fly (no pr[]/df[] arrays -> lower liveness)
template<int R, bool LAST>
DI void hpassC(const __half* __restrict__ xt, const __half* __restrict__ yt,
               __half* __restrict__ h0, __half* __restrict__ h1,
               const float* __restrict__ wk, int tid) {
  constexpr int K = 2 * R + 1;
  constexpr int LO = (16 - R) & ~3;
  constexpr int NW = (((19 + R) | 3) + 1) - LO;
  constexpr int OFS = (16 - R) - LO;
  for (int q = 0; q < 6; ++q) {
    int id = q * 256 + tid;
    int row = id >> 4, c0 = (id & 15) << 2;
    float fx[NW], fy[NW];
    load_win<NW>(xt + row * IW + c0 + LO, fx);
    load_win<NW>(yt + row * IW + c0 + LO, fy);
    float a0 = 0, a1 = 0, a2 = 0, a3 = 0, b0 = 0, b1 = 0, b2 = 0, b3 = 0;
#pragma unroll
    for (int j = 0; j < K; ++j) {
      float w = wk[j];
      a0 = fmaf(w, fx[OFS + j + 0] * fy[OFS + j + 0], a0);
      a1 = fmaf(w, fx[OFS + j + 1] * fy[OFS + j + 1], a1);
      a2 = fmaf(w, fx[OFS + j + 2] * fy[OFS + j + 2], a2);
      a3 = fmaf(w, fx[OFS + j + 3] * fy[OFS + j + 3], a3);
      if (LAST) {
        b0 = fmaf(w, fabsf(fx[OFS + j + 0] - fy[OFS + j + 0]), b0);
        b1 = fmaf(w, fabsf(fx[OFS + j + 1] - fy[OFS + j + 1]), b1);
        b2 = fmaf(w, fabsf(fx[OFS + j + 2] - fy[OFS + j + 2]), b2);
        b3 = fmaf(w, fabsf(fx[OFS + j + 3] - fy[OFS + j + 3]), b3);
      }
    }
    store4h(h0 + row * TW + c0, a0, a1, a2, a3);
    if (LAST) store4h(h1 + row * TW + c0, b0, b1, b2, b3);
  }
}

// ---- vertical pass: 4 rows x 4 cols per thread, 1 (or 2) maps ----
template<int R, bool TWO>
DI void vpass(const __half* __restrict__ h0, const __half* __restrict__ h1,
              const float* __restrict__ wk, int tid,
              float* __restrict__ acc0, float* __restrict__ acc1) {
  constexpr int K = 2 * R + 1;
  const int rg = tid >> 4, cg = tid & 15;
  const int r0 = rg << 2, c0 = cg << 2;
#pragma unroll
  for (int t = 0; t < K + 3; ++t) {
    int lr = r0 + (16 - R) + t;
    uint2 u = *reinterpret_cast<const uint2*>(h0 + lr * TW + c0);
    __half2 ha = *reinterpret_cast<__half2*>(&u.x);
    __half2 hb = *reinterpret_cast<__half2*>(&u.y);
    float x0 = __low2float(ha), x1 = __high2float(ha);
    float x2 = __low2float(hb), x3 = __high2float(hb);
    float y0 = 0, y1 = 0, y2 = 0, y3 = 0;
    if (TWO) {
      uint2 v = *reinterpret_cast<const uint2*>(h1 + lr * TW + c0);
      __half2 hc = *reinterpret_cast<__half2*>(&v.x);
      __half2 hd = *reinterpret_cast<__half2*>(&v.y);
      y0 = __low2float(hc); y1 = __high2float(hc);
      y2 = __low2float(hd); y3 = __high2float(hd);
    }
#pragma unroll
    for (int rr = 0; rr < 4; ++rr) {
      int j = t - rr;
      if (j >= 0 && j < K) {   // folds at compile time after unroll
        float w = wk[j];
        acc0[rr * 4 + 0] = fmaf(w, x0, acc0[rr * 4 + 0]);
        acc0[rr * 4 + 1] = fmaf(w, x1, acc0[rr * 4 + 1]);
        acc0[rr * 4 + 2] = fmaf(w, x2, acc0[rr * 4 + 2]);
        acc0[rr * 4 + 3] = fmaf(w, x3, acc0[rr * 4 + 3]);
        if (TWO) {
          acc1[rr * 4 + 0] = fmaf(w, y0, acc1[rr * 4 + 0]);
          acc1[rr * 4 + 1] = fmaf(w, y1, acc1[rr * 4 + 1]);
          acc1[rr * 4 + 2] = fmaf(w, y2, acc1[rr * 4 + 2]);
          acc1[rr * 4 + 3] = fmaf(w, y3, acc1[rr * 4 + 3]);
        }
      }
    }
  }
}

template<int R, bool LAST>
DI void do_sigma(int sidx, const float* __restrict__ w1d,
                 const __half* __restrict__ xt, const __half* __restrict__ yt,
                 __half* __restrict__ hb0, __half* __restrict__ hb1,
                 float* __restrict__ PIcs, float* __restrict__ lM,
                 float* __restrict__ gl1, int tid) {
  const float* wk = w1d + sidx * 33 + (16 - R);
  float mux[16], ex2[16], muy[16], ey2[16], exy[16], vl1[16];
#pragma unroll
  for (int i = 0; i < 16; ++i) {
    mux[i] = 0; ex2[i] = 0; muy[i] = 0; ey2[i] = 0; exy[i] = 0; vl1[i] = 0;
  }
  hpassAB<R>(xt, hb0, hb1, wk, tid);
  __syncthreads();
  vpass<R, true>(hb0, hb1, wk, tid, mux, ex2);
  __syncthreads();
  hpassAB<R>(yt, hb0, hb1, wk, tid);
  __syncthreads();
  vpass<R, true>(hb0, hb1, wk, tid, muy, ey2);
  __syncthreads();
  hpassC<R, LAST>(xt, yt, hb0, hb1, wk, tid);
  __syncthreads();
  vpass<R, LAST>(hb0, hb1, wk, tid, exy, vl1);
  __syncthreads();
#pragma unroll
  for (int i = 0; i < 16; ++i) {
    float m2x = mux[i] * mux[i];
    float m2y = muy[i] * muy[i];
    float mxy = mux[i] * muy[i];
    float sx2 = ex2[i] - m2x, sy2 = ey2[i] - m2y, sxy = exy[i] - mxy;
    float cs = fmaf(2.f, sxy, kC2) * rcp_fast(sx2 + sy2 + kC2);
    PIcs[i] *= cs;
    if (LAST) {
      float l = fmaf(2.f, mxy, kC1) * rcp_fast(m2x + m2y + kC1);
      lM[i] *= l;
      gl1[i] += vl1[i];
    }
  }
}

// ---- extract 1D separable kernels: g[j] = mask[16][j] / sqrt(mask[16][16]) ----
__global__ void prep_k(const float* __restrict__ gm, float* __restrict__ w1d) {
  int t = threadIdx.x;
  if (t < 165) {
    int s = t / 33, j = t % 33;
    const float* m = gm + (3 * s) * (33 * 33);
    float g16 = sqrtf(m[16 * 33 + 16]);
    w1d[t] = m[16 * 33 + j] / g16;
  }
}

// waves_per_eu(2,2): pin allocator to exactly 2 waves/EU -> 256-VGPR budget.
// Peak liveness ~210 regs (48 running products + 64 sigma partials + 36-wide
// h-window x2 + acc). With only min=2 (launch_bounds), backend targeted
// 128 VGPR and spilled ~2 GB of scratch to HBM (R0: WRITE_SIZE 1.25 GB).
__global__ __attribute__((amdgpu_flat_work_group_size(256, 256),
                          amdgpu_waves_per_eu(2, 2)))
void msloss_k(const float* __restrict__ x, const float* __restrict__ y,
              const float* __restrict__ w1d, float* __restrict__ out) {
  __shared__ __half xt[IH * IW];
  __shared__ __half yt[IH * IW];
  __shared__ __half hb0[IH * TW];
  __shared__ __half hb1[IH * TW];
  __shared__ float red[4];
  const int tid = threadIdx.x;
  const int ox = blockIdx.x * TW, oy = blockIdx.y * TH;
  const int b = blockIdx.z;

  float PIcs[16], lM[16], gl1[16];
#pragma unroll
  for (int i = 0; i < 16; ++i) { PIcs[i] = 1.f; lM[i] = 1.f; gl1[i] = 0.f; }

  for (int c = 0; c < 3; ++c) {
    const float* xp = x + (size_t)(b * 3 + c) * (512 * 512);
    const float* yp = y + (size_t)(b * 3 + c) * (512 * 512);
    // stage 96x96 fp32->fp16 tiles with zero halo (2304 float4 slots each)
    for (int t = 0; t < 9; ++t) {
      int idx = t * 256 + tid;
      int row = idx / 24, c4 = idx % 24;
      int gy = oy + row - 16, gx = ox + c4 * 4 - 16;
      bool ok = ((unsigned)gy < 512u) && ((unsigned)gx < 512u);
      float4 xv = make_float4(0.f, 0.f, 0.f, 0.f);
      float4 yv = make_float4(0.f, 0.f, 0.f, 0.f);
      if (ok) {
        xv = *reinterpret_cast<const float4*>(xp + gy * 512 + gx);
        yv = *reinterpret_cast<const float4*>(yp + gy * 512 + gx);
      }
      store4h(xt + row * IW + c4 * 4, xv.x, xv.y, xv.z, xv.w);
      store4h(yt + row * IW + c4 * 4, yv.x, yv.y, yv.z, yv.w);
    }
    __syncthreads();
    do_sigma<4, false>(0, w1d, xt, yt, hb0, hb1, PIcs, lM, gl1, tid);
    do_sigma<6, false>(1, w1d, xt, yt, hb0, hb1, PIcs, lM, gl1, tid);
    do_sigma<12, false>(2, w1d, xt, yt, hb0, hb1, PIcs, lM, gl1, tid);
    do_sigma<16, false>(3, w1d, xt, yt, hb0, hb1, PIcs, lM, gl1, tid);
    do_sigma<16, true>(4, w1d, xt, yt, hb0, hb1, PIcs, lM, gl1, tid);
    // do_sigma ends with __syncthreads(): safe to restage next channel
  }

  float s = 0.f;
#pragma unroll
  for (int i = 0; i < 16; ++i)
    s += kALPHA * (1.f - lM[i] * PIcs[i]) + ((1.f - kALPHA) / 3.f) * gl1[i];
#pragma unroll
  for (int off = 32; off > 0; off >>= 1) s += __shfl_down(s, off);
  if ((tid & 63) == 0) red[tid >> 6] = s;
  __syncthreads();
  if (tid == 0)
    atomicAdd(out, (red[0] + red[1] + red[2] + red[3]) *
                       (200.0f / (8.0f * 512.0f * 512.0f)));
}

extern "C" void kernel_launch(void* const* d_in, const int* in_sizes, int n_in,
                              void* d_out, int out_size, void* d_ws, size_t ws_size,
                              hipStream_t stream) {
  const float* x = (const float*)d_in[0];
  const float* y = (const float*)d_in[1];
  const float* gm = (const float*)d_in[2];
  float* out = (float*)d_out;
  float* w1d = (float*)d_ws;  // 165 floats of 1D kernels

  hipMemsetAsync(d_out, 0, out_size * sizeof(float), stream);
  prep_k<<<1, 256, 0, stream>>>(gm, w1d);
  msloss_k<<<dim3(8, 8, 8), 256, 0, stream>>>(x, y, w1d, out);
}